// Round 6
// baseline (511.938 us; speedup 1.0000x reference)
//
#include <hip/hip_runtime.h>
#include <hip/hip_bf16.h>

#define Nn 200000
#define Cc 1000
#define Dd 256
#define PAD 16   // counter padding (one per 64B line) to kill atomic line contention

typedef float f32x16 __attribute__((ext_vector_type(16)));
typedef short bf16x8 __attribute__((ext_vector_type(8)));

#define LOG2E  1.4426950408889634f
#define LOG2E2 2.8853900817779268f

__device__ __forceinline__ unsigned short f2bf(float x){
    union { float f; unsigned int u; } c; c.f = x;
    unsigned int u = c.u;
    u += 0x7fffu + ((u >> 16) & 1u);   // round-to-nearest-even
    return (unsigned short)(u >> 16);
}
__device__ __forceinline__ float bf2f(unsigned short b){
    union { unsigned int u; float f; } c; c.u = ((unsigned int)b) << 16;
    return c.f;
}
__device__ __forceinline__ float rcp_(float x){ return __builtin_amdgcn_rcpf(x); }

// ---------------- weight prep: Wcat_t[col][k] bf16 (col 0..255 = Wk, 256..511 = H1w); zero padded hist ----------------
__global__ void k_prep_wcat(const float* __restrict__ Wk, const float* __restrict__ H1w,
                            unsigned short* __restrict__ wcat, int* __restrict__ hist){
    int i = blockIdx.x * 256 + threadIdx.x;       // 512 blocks x 256
    if (i < Cc*PAD) hist[i] = 0;
    int col = i >> 8, k = i & 255;
    float w = (col < Dd) ? Wk[k*Dd + col] : H1w[k*Dd + (col - Dd)];
    wcat[col*Dd + k] = f2bf(w);
}

// ---------------- per-cluster precompute (1000 blocks) + node histogram fused ----------------
__global__ __launch_bounds__(256)
void k_cluster_prep(const float* __restrict__ g, const float* __restrict__ Wq,
                    const float* __restrict__ b_attn,
                    const float* __restrict__ Ws, const float* __restrict__ bs,
                    const float* __restrict__ G1w, const float* __restrict__ G1b,
                    const float* __restrict__ H1b,
                    const int* __restrict__ seg, int* __restrict__ hist,
                    float* __restrict__ qb, float* __restrict__ h_trans,
                    float* __restrict__ cterm){
    int c = blockIdx.x, d = threadIdx.x;
    int gi = c*256 + d;
    if (gi < Nn) atomicAdd(&hist[seg[gi]*PAD], 1);   // padded counters
    __shared__ float gL[Dd], htL[Dd];
    gL[d] = g[(size_t)c*Dd + d];
    __syncthreads();
    float aq = b_attn[d], as = bs[d];
    #pragma unroll 4
    for (int k = 0; k < Dd; ++k){
        float gv = gL[k];
        aq = fmaf(gv, Wq[k*Dd + d], aq);
        as = fmaf(gv, Ws[k*Dd + d], as);
    }
    qb[(size_t)c*Dd + d] = aq;
    float ht = tanhf(as);
    h_trans[(size_t)c*Dd + d] = ht;
    htL[d] = ht;
    __syncthreads();
    float ac = H1b[d] + G1b[d];
    #pragma unroll 4
    for (int k = 0; k < Dd; ++k) ac = fmaf(htL[k], G1w[k*Dd + d], ac);
    cterm[(size_t)c*Dd + d] = ac;
}

// ---------------- counting sort: scan + scatter (padded counters) ----------------
__global__ void k_scan(const int* __restrict__ hist, int* __restrict__ offs, int* __restrict__ cursor){
    __shared__ int sc[1024];
    int t = threadIdx.x;
    int v = (t < Cc) ? hist[t*PAD] : 0;
    sc[t] = v;
    __syncthreads();
    for (int off = 1; off < 1024; off <<= 1){
        int add = (t >= off) ? sc[t - off] : 0;
        __syncthreads();
        sc[t] += add;
        __syncthreads();
    }
    if (t < Cc){
        int excl = sc[t] - v;
        offs[t] = excl;
        cursor[t*PAD] = excl;
    }
}
__global__ void k_scatter(const int* __restrict__ seg, int* __restrict__ cursor, int* __restrict__ order){
    int i = blockIdx.x*256 + threadIdx.x;
    if (i < Nn){
        int p = atomicAdd(&cursor[seg[i]*PAD], 1);
        order[p] = i;
    }
}

// ---------------- big fused kernel, swapped-operand form:
//   acc = mfma_32x32x16( A = Wcat[colTile][k], B = h^T[k][nodeTile] )  ->  D = Y^T[col][node]
//   Each lane: node = nb+(l&31); 4 col-groups of 4 consecutive cols -> float4 epilogue directly
//   on fragments. No yS stage; only 2 barriers total. ----------------
__global__ __launch_bounds__(512, 2)
void k_gemm_fused(const float* __restrict__ h,
                  const unsigned short* __restrict__ wcat,
                  const int* __restrict__ seg,
                  const float* __restrict__ qb,
                  const float* __restrict__ w_score,
                  const float* __restrict__ b_score,
                  const float* __restrict__ cterm,
                  const float* __restrict__ h_trans,
                  float* __restrict__ e,
                  float* __restrict__ out){
    __shared__ __align__(16) char aT[64*512];   // 32 KiB bf16 A(h) tile, XOR-swizzled (row&15)<<4
    __shared__ float sPart[64][4];
    __shared__ int segL[64];

    int tid = threadIdx.x;
    int w = tid >> 6, l = tid & 63;
    int rowBase = blockIdx.x * 64;

    // ---- stage h tile: 8 float4 loads, fp32->bf16, swizzled LDS writes ----
    {
        const float4* hv = reinterpret_cast<const float4*>(h + (size_t)rowBase * Dd);
        float4 v[8];
        #pragma unroll
        for (int j = 0; j < 8; ++j) v[j] = hv[j*512 + tid];
        if (tid < 64) segL[tid] = seg[rowBase + tid];
        #pragma unroll
        for (int j = 0; j < 8; ++j){
            int f = j*512 + tid;
            int row = f >> 6;
            unsigned long long pk = (unsigned long long)f2bf(v[j].x)
                                  | ((unsigned long long)f2bf(v[j].y) << 16)
                                  | ((unsigned long long)f2bf(v[j].z) << 32)
                                  | ((unsigned long long)f2bf(v[j].w) << 48);
            int byte = (row*512 + (f & 63)*8) ^ ((row & 15) << 4);
            *reinterpret_cast<unsigned long long*>(aT + byte) = pk;
        }
    }
    __syncthreads();

    int ct   = w & 3;            // col sub-tile (32 cols) within the 128-col pass
    int nb   = (w >> 2) * 32;    // node base (0 or 32)
    int lNode = l & 31;
    int hiK  = l >> 5;           // k-half selector
    int node = nb + lNode;
    int sgt  = segL[node];
    int swzR = (node & 15) << 4;
    int hBase0 = node*512 + hiK*16;
    const char* wPtr = reinterpret_cast<const char*>(wcat) + (size_t)(ct*32 + lNode)*512 + hiK*16;
    float bsc = b_score[0];
    float sp  = 0.f;

    f32x16 acc;

    // epilogue on fragments of pass pe (Y^T layout: lane holds cols colBase+8g+4*hiK..+3 for `node`)
    auto epi = [&](int pe, const f32x16& A){
        int colBase = pe*128 + ct*32;
        if (pe < 2){
            #pragma unroll
            for (int g = 0; g < 4; ++g){
                int cb = colBase + 8*g + 4*hiK;
                float4 q4 = *reinterpret_cast<const float4*>(qb + (size_t)sgt*Dd + cb);
                float4 w4 = *reinterpret_cast<const float4*>(w_score + cb);
                float t;
                t = exp2f(LOG2E2*(A[4*g+0] + q4.x)); sp = fmaf((t-1.f)*rcp_(t+1.f), w4.x, sp);
                t = exp2f(LOG2E2*(A[4*g+1] + q4.y)); sp = fmaf((t-1.f)*rcp_(t+1.f), w4.y, sp);
                t = exp2f(LOG2E2*(A[4*g+2] + q4.z)); sp = fmaf((t-1.f)*rcp_(t+1.f), w4.z, sp);
                t = exp2f(LOG2E2*(A[4*g+3] + q4.w)); sp = fmaf((t-1.f)*rcp_(t+1.f), w4.w, sp);
            }
            if (pe == 1){
                sp += __shfl_xor(sp, 32);          // combine the two k-half col sets (same node)
                if (l < 32) sPart[node][ct] = sp;
                __syncthreads();
                if (tid < 64){
                    float s = sPart[tid][0] + sPart[tid][1] + sPart[tid][2] + sPart[tid][3] + bsc;
                    e[rowBase + tid] = exp2f(LOG2E * s);   // unshifted exp: |s| small, ratio == ref
                }
            }
        } else {
            #pragma unroll
            for (int g = 0; g < 4; ++g){
                int oc = (colBase - 256) + 8*g + 4*hiK;
                float4 c4 = *reinterpret_cast<const float4*>(cterm   + (size_t)sgt*Dd + oc);
                float4 t4 = *reinterpret_cast<const float4*>(h_trans + (size_t)sgt*Dd + oc);
                unsigned long long hb =
                    *reinterpret_cast<const unsigned long long*>(aT + ((node*512 + oc*2) ^ swzR));
                float h0 = bf2f((unsigned short)(hb      ));
                float h1 = bf2f((unsigned short)(hb >> 16));
                float h2 = bf2f((unsigned short)(hb >> 32));
                float h3 = bf2f((unsigned short)(hb >> 48));
                float4 o4; float z;
                z = rcp_(1.f + exp2f(-LOG2E*(A[4*g+0] + c4.x))); o4.x = fmaf(z, t4.x - h0, h0);
                z = rcp_(1.f + exp2f(-LOG2E*(A[4*g+1] + c4.y))); o4.y = fmaf(z, t4.y - h1, h1);
                z = rcp_(1.f + exp2f(-LOG2E*(A[4*g+2] + c4.z))); o4.z = fmaf(z, t4.z - h2, h2);
                z = rcp_(1.f + exp2f(-LOG2E*(A[4*g+3] + c4.w))); o4.w = fmaf(z, t4.w - h3, h3);
                *reinterpret_cast<float4*>(out + (size_t)(rowBase + node)*Dd + oc) = o4;
            }
        }
    };

    for (int p = 0; p < 4; ++p){
        const char* wb = wPtr + (size_t)p * 128 * 512;
        bf16x8 wA[8], wB[8];
        #pragma unroll
        for (int kk = 0; kk < 8; ++kk)
            wA[kk] = *reinterpret_cast<const bf16x8*>(wb + kk*32);          // k-steps 0..7

        if (p > 0) epi(p - 1, acc);   // previous pass's epilogue hides wA L2 latency

        #pragma unroll
        for (int kk = 0; kk < 8; ++kk)
            wB[kk] = *reinterpret_cast<const bf16x8*>(wb + 256 + kk*32);    // k-steps 8..15

        #pragma unroll
        for (int i = 0; i < 16; ++i) acc[i] = 0.f;

        #pragma unroll
        for (int kk = 0; kk < 8; ++kk){
            bf16x8 hF = *reinterpret_cast<const bf16x8*>(aT + ((hBase0 + kk*32) ^ swzR));
            acc = __builtin_amdgcn_mfma_f32_32x32x16_bf16(wA[kk], hF, acc, 0, 0, 0);
        }
        #pragma unroll
        for (int kk = 0; kk < 8; ++kk){
            bf16x8 hF = *reinterpret_cast<const bf16x8*>(aT + ((hBase0 + 256 + kk*32) ^ swzR));
            acc = __builtin_amdgcn_mfma_f32_32x32x16_bf16(wB[kk], hF, acc, 0, 0, 0);
        }
    }
    epi(3, acc);
}

// ---------------- per-cluster ctx partials: 4 chunk-blocks per cluster, no atomics ----------------
__global__ __launch_bounds__(256)
void k_ctx(const float* __restrict__ h, const float* __restrict__ e,
           const int* __restrict__ order, const int* __restrict__ hist,
           const int* __restrict__ offs,
           float* __restrict__ ctxPart, float* __restrict__ denPart){
    int b = blockIdx.x;              // 0..3999
    int c = b >> 2, q = b & 3;
    int cnt = hist[c*PAD], start0 = offs[c];
    int c0 = (cnt * q) >> 2, c1 = (cnt * (q+1)) >> 2;
    int n = c1 - c0;
    int start = start0 + c0;
    int t = threadIdx.x;
    __shared__ int idxL[512];
    __shared__ float eL[512];
    __shared__ float redL[4][256];
    __shared__ float dsum[4];
    int r4 = t >> 6;                 // wave id: rows == r4 mod 4
    int col4 = (t & 63) << 2;        // float4 column
    float ax = 0.f, ay = 0.f, az = 0.f, aw = 0.f;
    float dpart = 0.f;
    for (int base = 0; base < n; base += 512){
        int m = min(512, n - base);
        for (int i = t; i < m; i += 256){
            int nd = order[start + base + i];
            idxL[i] = nd;
            float ev = e[nd];
            eL[i] = ev;
            dpart += ev;
        }
        __syncthreads();
        #pragma unroll 4
        for (int i = r4; i < m; i += 4){
            float ev = eL[i];
            float4 hv = *reinterpret_cast<const float4*>(h + (size_t)idxL[i]*Dd + col4);
            ax = fmaf(ev, hv.x, ax);
            ay = fmaf(ev, hv.y, ay);
            az = fmaf(ev, hv.z, az);
            aw = fmaf(ev, hv.w, aw);
        }
        __syncthreads();
    }
    *reinterpret_cast<float4*>(&redL[r4][col4]) = (float4){ax, ay, az, aw};
    #pragma unroll
    for (int off = 1; off < 64; off <<= 1) dpart += __shfl_xor(dpart, off);
    if ((t & 63) == 0) dsum[r4] = dpart;
    __syncthreads();
    if (t < 256){
        float s = redL[0][t] + redL[1][t] + redL[2][t] + redL[3][t];
        ctxPart[((size_t)c*4 + q)*Dd + t] = s;
    }
    if (t == 0) denPart[b] = dsum[0] + dsum[1] + dsum[2] + dsum[3];
}

// ---------------- virtual-node side (1 cluster/block): combine ctx partials, then
//                  g_trans = tanh(ctx@Wv+bv); z2 gate; out rows N..N+C-1 ----------------
__global__ __launch_bounds__(256)
void k_vn(const float* __restrict__ ctxPart, const float* __restrict__ denPart,
          const float* __restrict__ g_hat,
          const float* __restrict__ Wv, const float* __restrict__ bv,
          const float* __restrict__ H2w, const float* __restrict__ H2b,
          const float* __restrict__ G2w, const float* __restrict__ G2b,
          float* __restrict__ out){
    int c = blockIdx.x, d = threadIdx.x;
    __shared__ float cL[Dd], gtL[Dd], ghL[Dd];
    float den = denPart[c*4] + denPart[c*4+1] + denPart[c*4+2] + denPart[c*4+3];
    float inv = (den > 0.f) ? 1.f/den : 0.f;   // empty cluster -> ctx = 0 (matches ref)
    float num = ctxPart[((size_t)c*4 + 0)*Dd + d] + ctxPart[((size_t)c*4 + 1)*Dd + d]
              + ctxPart[((size_t)c*4 + 2)*Dd + d] + ctxPart[((size_t)c*4 + 3)*Dd + d];
    cL[d]  = num * inv;
    ghL[d] = g_hat[(size_t)c*Dd + d];
    __syncthreads();
    float a1 = bv[d];
    #pragma unroll 4
    for (int k = 0; k < Dd; ++k) a1 = fmaf(cL[k], Wv[k*Dd + d], a1);
    float gt = tanhf(a1);
    gtL[d] = gt;
    __syncthreads();
    float a2 = H2b[d] + G2b[d];
    #pragma unroll 4
    for (int k = 0; k < Dd; ++k){
        a2 = fmaf(gtL[k], H2w[k*Dd + d], a2);
        a2 = fmaf(ghL[k], G2w[k*Dd + d], a2);
    }
    float z = 1.f / (1.f + expf(-a2));
    out[(size_t)(Nn + c)*Dd + d] = (1.f - z)*gt + z*ghL[d];
}

extern "C" void kernel_launch(void* const* d_in, const int* in_sizes, int n_in,
                              void* d_out, int out_size, void* d_ws, size_t ws_size,
                              hipStream_t stream){
    const float* h       = (const float*)d_in[0];
    const float* g       = (const float*)d_in[1];
    const float* g_hat   = (const float*)d_in[2];
    const int*   seg     = (const int*)  d_in[3];
    const float* Wq      = (const float*)d_in[4];
    const float* Wk      = (const float*)d_in[5];
    const float* b_attn  = (const float*)d_in[6];
    const float* w_score = (const float*)d_in[7];
    const float* b_score = (const float*)d_in[8];
    const float* Wv      = (const float*)d_in[9];
    const float* bv      = (const float*)d_in[10];
    const float* Ws      = (const float*)d_in[11];
    const float* bs      = (const float*)d_in[12];
    const float* H1w     = (const float*)d_in[13];
    const float* H1b     = (const float*)d_in[14];
    const float* G1w     = (const float*)d_in[15];
    const float* G1b     = (const float*)d_in[16];
    const float* H2w     = (const float*)d_in[17];
    const float* H2b     = (const float*)d_in[18];
    const float* G2w     = (const float*)d_in[19];
    const float* G2b     = (const float*)d_in[20];
    float* out = (float*)d_out;

    char* ws = (char*)d_ws;
    unsigned short* wcat = (unsigned short*)(ws + 0);        //   262,144 B
    float* qb      = (float*)(ws +  262144);                 // 1,024,000 B
    float* h_trans = (float*)(ws + 1286144);                 // 1,024,000 B
    float* cterm   = (float*)(ws + 2310144);                 // 1,024,000 B
    float* e       = (float*)(ws + 3334144);                 //   800,000 B
    int*   order   = (int*)  (ws + 4134144);                 //   800,000 B
    int*   hist    = (int*)  (ws + 4934144);                 //    64,000 B (padded x16)
    int*   offs    = (int*)  (ws + 4998144);                 //     4,000 B
    int*   cursor  = (int*)  (ws + 5002144);                 //    64,000 B (padded x16)
    float* ctxPart = (float*)(ws + 5066144);                 // 4,096,000 B
    float* denPart = (float*)(ws + 9162144);                 //    16,000 B

    hipLaunchKernelGGL(k_prep_wcat, dim3(512), dim3(256), 0, stream, Wk, H1w, wcat, hist);
    hipLaunchKernelGGL(k_cluster_prep, dim3(Cc), dim3(256), 0, stream,
                       g, Wq, b_attn, Ws, bs, G1w, G1b, H1b, seg, hist, qb, h_trans, cterm);
    hipLaunchKernelGGL(k_scan, dim3(1), dim3(1024), 0, stream, hist, offs, cursor);
    hipLaunchKernelGGL(k_scatter, dim3((Nn + 255)/256), dim3(256), 0, stream, seg, cursor, order);
    hipLaunchKernelGGL(k_gemm_fused, dim3(Nn/64), dim3(512), 0, stream,
                       h, wcat, seg, qb, w_score, b_score, cterm, h_trans, e, out);
    hipLaunchKernelGGL(k_ctx, dim3(Cc*4), dim3(256), 0, stream, h, e, order, hist, offs, ctxPart, denPart);
    hipLaunchKernelGGL(k_vn, dim3(Cc), dim3(256), 0, stream,
                       ctxPart, denPart, g_hat, Wv, bv, H2w, H2b, G2w, G2b, out);
}

// Round 7
// 383.327 us; speedup vs baseline: 1.3355x; 1.3355x over previous
//
#include <hip/hip_runtime.h>
#include <hip/hip_bf16.h>

#define Nn 200000
#define Cc 1000
#define Dd 256
#define PAD 16        // counter padding (one per 64B line)
#define NCHUNK 6250   // Nn / 32
#define GBLK 250      // gemm grid: 250 blocks x 25 chunks each

typedef float f32x16 __attribute__((ext_vector_type(16)));
typedef short bf16x8 __attribute__((ext_vector_type(8)));

#define LOG2E  1.4426950408889634f
#define LOG2E2 2.8853900817779268f

__device__ __forceinline__ unsigned int f2bf(float x){
    union { float f; unsigned int u; } c; c.f = x;
    unsigned int u = c.u;
    u += 0x7fffu + ((u >> 16) & 1u);   // round-to-nearest-even
    return u >> 16;
}
__device__ __forceinline__ float bf2f(unsigned short b){
    union { unsigned int u; float f; } c; c.u = ((unsigned int)b) << 16;
    return c.f;
}
__device__ __forceinline__ float rcp_(float x){ return __builtin_amdgcn_rcpf(x); }

// ---------------- prep: W fragment tables (MFMA 32x32x16 operand order) + zero hist ----------------
// slot s = (ct*16 + kk)*64 + lane ; elem e:  value = W[k][col], col = ct*32 + (lane&31),
// k = kk*16 + (lane>>5)*8 + e.  A wave's (ct,kk) fragment is 1 KB contiguous.
__global__ void k_prep(const float* __restrict__ Wk, const float* __restrict__ H1w,
                       unsigned short* __restrict__ wfragK, unsigned short* __restrict__ wfragH,
                       int* __restrict__ hist){
    int t = blockIdx.x*256 + threadIdx.x;       // 64 x 256 = 16384
    if (t < Cc*PAD) hist[t] = 0;
    int arr = t >> 13;
    int s   = t & 8191;
    int ct  = s >> 10;
    int kk  = (s >> 6) & 15;
    int l   = s & 63;
    int col = ct*32 + (l & 31);
    int k0  = kk*16 + (l >> 5)*8;
    const float* W = arr ? H1w : Wk;
    unsigned short* dst = (arr ? wfragH : wfragK) + (size_t)s*8;
    #pragma unroll
    for (int e = 0; e < 8; ++e) dst[e] = (unsigned short)f2bf(W[(size_t)(k0+e)*Dd + col]);
}

// ---------------- per-cluster precompute (1000 blocks) + node histogram fused ----------------
__global__ __launch_bounds__(256)
void k_cluster_prep(const float* __restrict__ g, const float* __restrict__ Wq,
                    const float* __restrict__ b_attn,
                    const float* __restrict__ Ws, const float* __restrict__ bs,
                    const float* __restrict__ G1w, const float* __restrict__ G1b,
                    const float* __restrict__ H1b,
                    const int* __restrict__ seg, int* __restrict__ hist,
                    float* __restrict__ qb, float* __restrict__ h_trans,
                    float* __restrict__ cterm){
    int c = blockIdx.x, d = threadIdx.x;
    int gi = c*256 + d;
    if (gi < Nn) atomicAdd(&hist[seg[gi]*PAD], 1);
    __shared__ float gL[Dd], htL[Dd];
    gL[d] = g[(size_t)c*Dd + d];
    __syncthreads();
    float aq = b_attn[d], as = bs[d];
    #pragma unroll 4
    for (int k = 0; k < Dd; ++k){
        float gv = gL[k];
        aq = fmaf(gv, Wq[k*Dd + d], aq);
        as = fmaf(gv, Ws[k*Dd + d], as);
    }
    qb[(size_t)c*Dd + d] = aq;
    float ht = tanhf(as);
    h_trans[(size_t)c*Dd + d] = ht;
    htL[d] = ht;
    __syncthreads();
    float ac = H1b[d] + G1b[d];
    #pragma unroll 4
    for (int k = 0; k < Dd; ++k) ac = fmaf(htL[k], G1w[k*Dd + d], ac);
    cterm[(size_t)c*Dd + d] = ac;
}

// ---------------- counting sort: scan + scatter (padded counters) ----------------
__global__ void k_scan(const int* __restrict__ hist, int* __restrict__ offs, int* __restrict__ cursor){
    __shared__ int sc[1024];
    int t = threadIdx.x;
    int v = (t < Cc) ? hist[t*PAD] : 0;
    sc[t] = v;
    __syncthreads();
    for (int off = 1; off < 1024; off <<= 1){
        int add = (t >= off) ? sc[t - off] : 0;
        __syncthreads();
        sc[t] += add;
        __syncthreads();
    }
    if (t < Cc){
        int excl = sc[t] - v;
        offs[t] = excl;
        cursor[t*PAD] = excl;
    }
}
__global__ void k_scatter(const int* __restrict__ seg, int* __restrict__ cursor, int* __restrict__ order){
    int i = blockIdx.x*256 + threadIdx.x;
    if (i < Nn){
        int p = atomicAdd(&cursor[seg[i]*PAD], 1);
        order[p] = i;
    }
}

// ================= score GEMM: Wk fully in LDS; VMEM-free k-loop =================
// Block: Wk-frags 128 KB resident; 25 chunks of 32 nodes. Wave w owns col-tile ct=w (32 cols).
// Per chunk: stage A (32x256 bf16, swizzled), 16 MFMAs/wave, epilogue computes e[node].
__global__ __launch_bounds__(512, 2)
void k_score(const float* __restrict__ h, const unsigned short* __restrict__ wfrag,
             const int* __restrict__ seg, const float* __restrict__ qb,
             const float* __restrict__ w_score, const float* __restrict__ b_score,
             float* __restrict__ e){
    __shared__ __align__(16) char Wl[131072];   // 128 KB W fragments (linear copy)
    __shared__ __align__(16) char Al[16384];    // 16 KB A tile: 32 nodes x 512B, XOR-swizzled
    __shared__ float sPart[32][8];

    int tid = threadIdx.x;
    int w = tid >> 6, l = tid & 63;

    // stage W once (coalesced 16B copies)
    {
        const float4* src = reinterpret_cast<const float4*>(wfrag);
        float4* dst = reinterpret_cast<float4*>(Wl);
        #pragma unroll
        for (int i = 0; i < 16; ++i) dst[i*512 + tid] = src[i*512 + tid];
    }

    int ct = w;
    int lNode = l & 31, hiK = l >> 5;
    int swz = (lNode & 15) << 4;
    int nodeT = tid >> 4;              // staging: node 0..31 (16 threads/node)
    int sw2 = (nodeT & 15) << 4;
    int c0 = (tid & 15) * 2;           // staging: two 16B bf16 chunks per thread
    int sb0 = nodeT*512 + ((c0*16) ^ sw2);
    int sb1 = sb0 ^ 16;
    float bsc = b_score[0];

    int ch = blockIdx.x;
    float4 r[4];
    {
        const float4* hv = reinterpret_cast<const float4*>(h + (size_t)ch*32*Dd);
        #pragma unroll
        for (int j = 0; j < 4; ++j) r[j] = hv[nodeT*64 + (tid & 15)*4 + j];
    }
    __syncthreads();   // W staged

    for (; ch < NCHUNK; ch += GBLK){
        // ---- write A tile from regs (bf16 pack, swizzled) ----
        uint4 A0, A1;
        A0.x = f2bf(r[0].x) | (f2bf(r[0].y) << 16);
        A0.y = f2bf(r[0].z) | (f2bf(r[0].w) << 16);
        A0.z = f2bf(r[1].x) | (f2bf(r[1].y) << 16);
        A0.w = f2bf(r[1].z) | (f2bf(r[1].w) << 16);
        A1.x = f2bf(r[2].x) | (f2bf(r[2].y) << 16);
        A1.y = f2bf(r[2].z) | (f2bf(r[2].w) << 16);
        A1.z = f2bf(r[3].x) | (f2bf(r[3].y) << 16);
        A1.w = f2bf(r[3].z) | (f2bf(r[3].w) << 16);
        *reinterpret_cast<uint4*>(Al + sb0) = A0;
        *reinterpret_cast<uint4*>(Al + sb1) = A1;
        __syncthreads();   // A ready

        // ---- prefetch next chunk (flies under k-loop + epilogue) ----
        int nch = ch + GBLK;
        if (nch < NCHUNK){
            const float4* hv = reinterpret_cast<const float4*>(h + (size_t)nch*32*Dd);
            #pragma unroll
            for (int j = 0; j < 4; ++j) r[j] = hv[nodeT*64 + (tid & 15)*4 + j];
        }

        // ---- k-loop: LDS only ----
        f32x16 acc;
        #pragma unroll
        for (int i = 0; i < 16; ++i) acc[i] = 0.f;
        const char* wbase = Wl + (size_t)(ct*16)*1024;
        #pragma unroll
        for (int kk = 0; kk < 16; ++kk){
            bf16x8 wF = *reinterpret_cast<const bf16x8*>(wbase + kk*1024 + l*16);
            bf16x8 hF = *reinterpret_cast<const bf16x8*>(Al + lNode*512 + ((kk*32 + hiK*16) ^ swz));
            acc = __builtin_amdgcn_mfma_f32_32x32x16_bf16(wF, hF, acc, 0, 0, 0);
        }

        // ---- epilogue: sp = sum over this wave's 32 cols of tanh(y+qb[seg])*w_score ----
        int nodeG = ch*32 + lNode;
        int sgt = seg[nodeG];
        float sp = 0.f;
        #pragma unroll
        for (int g = 0; g < 4; ++g){
            int cb = ct*32 + 8*g + 4*hiK;
            float4 q4 = *reinterpret_cast<const float4*>(qb + (size_t)sgt*Dd + cb);
            float4 w4 = *reinterpret_cast<const float4*>(w_score + cb);
            float t;
            t = exp2f(LOG2E2*(acc[4*g+0] + q4.x)); sp = fmaf((t-1.f)*rcp_(t+1.f), w4.x, sp);
            t = exp2f(LOG2E2*(acc[4*g+1] + q4.y)); sp = fmaf((t-1.f)*rcp_(t+1.f), w4.y, sp);
            t = exp2f(LOG2E2*(acc[4*g+2] + q4.z)); sp = fmaf((t-1.f)*rcp_(t+1.f), w4.z, sp);
            t = exp2f(LOG2E2*(acc[4*g+3] + q4.w)); sp = fmaf((t-1.f)*rcp_(t+1.f), w4.w, sp);
        }
        sp += __shfl_xor(sp, 32);          // combine k-halves (same node)
        if (l < 32) sPart[lNode][w] = sp;
        __syncthreads();                   // sPart visible
        if (tid < 32){
            float s = sPart[tid][0] + sPart[tid][1] + sPart[tid][2] + sPart[tid][3]
                    + sPart[tid][4] + sPart[tid][5] + sPart[tid][6] + sPart[tid][7] + bsc;
            e[ch*32 + tid] = exp2f(LOG2E * s);   // unshifted exp: |s| small, ratio == ref
        }
        __syncthreads();                   // protect Al/sPart before next chunk
    }
}

// ================= merge GEMM: H1w fully in LDS; VMEM-free k-loop =================
__global__ __launch_bounds__(512, 2)
void k_merge(const float* __restrict__ h, const unsigned short* __restrict__ wfrag,
             const int* __restrict__ seg, const float* __restrict__ cterm,
             const float* __restrict__ h_trans, float* __restrict__ out){
    __shared__ __align__(16) char Wl[131072];
    __shared__ __align__(16) char Al[16384];

    int tid = threadIdx.x;
    int w = tid >> 6, l = tid & 63;
    {
        const float4* src = reinterpret_cast<const float4*>(wfrag);
        float4* dst = reinterpret_cast<float4*>(Wl);
        #pragma unroll
        for (int i = 0; i < 16; ++i) dst[i*512 + tid] = src[i*512 + tid];
    }
    int ct = w;
    int lNode = l & 31, hiK = l >> 5;
    int swz = (lNode & 15) << 4;
    int nodeT = tid >> 4;
    int sw2 = (nodeT & 15) << 4;
    int c0 = (tid & 15) * 2;
    int sb0 = nodeT*512 + ((c0*16) ^ sw2);
    int sb1 = sb0 ^ 16;

    int ch = blockIdx.x;
    float4 r[4];
    {
        const float4* hv = reinterpret_cast<const float4*>(h + (size_t)ch*32*Dd);
        #pragma unroll
        for (int j = 0; j < 4; ++j) r[j] = hv[nodeT*64 + (tid & 15)*4 + j];
    }
    __syncthreads();

    for (; ch < NCHUNK; ch += GBLK){
        uint4 A0, A1;
        A0.x = f2bf(r[0].x) | (f2bf(r[0].y) << 16);
        A0.y = f2bf(r[0].z) | (f2bf(r[0].w) << 16);
        A0.z = f2bf(r[1].x) | (f2bf(r[1].y) << 16);
        A0.w = f2bf(r[1].z) | (f2bf(r[1].w) << 16);
        A1.x = f2bf(r[2].x) | (f2bf(r[2].y) << 16);
        A1.y = f2bf(r[2].z) | (f2bf(r[2].w) << 16);
        A1.z = f2bf(r[3].x) | (f2bf(r[3].y) << 16);
        A1.w = f2bf(r[3].z) | (f2bf(r[3].w) << 16);
        *reinterpret_cast<uint4*>(Al + sb0) = A0;
        *reinterpret_cast<uint4*>(Al + sb1) = A1;
        __syncthreads();

        int nch = ch + GBLK;
        if (nch < NCHUNK){
            const float4* hv = reinterpret_cast<const float4*>(h + (size_t)nch*32*Dd);
            #pragma unroll
            for (int j = 0; j < 4; ++j) r[j] = hv[nodeT*64 + (tid & 15)*4 + j];
        }

        f32x16 acc;
        #pragma unroll
        for (int i = 0; i < 16; ++i) acc[i] = 0.f;
        const char* wbase = Wl + (size_t)(ct*16)*1024;
        #pragma unroll
        for (int kk = 0; kk < 16; ++kk){
            bf16x8 wF = *reinterpret_cast<const bf16x8*>(wbase + kk*1024 + l*16);
            bf16x8 hF = *reinterpret_cast<const bf16x8*>(Al + lNode*512 + ((kk*32 + hiK*16) ^ swz));
            acc = __builtin_amdgcn_mfma_f32_32x32x16_bf16(wF, hF, acc, 0, 0, 0);
        }

        // ---- epilogue: z1 = sigmoid(y + cterm[seg]); out = h + z*(h_trans[seg]-h) ----
        int nodeG = ch*32 + lNode;
        int sgt = seg[nodeG];
        #pragma unroll
        for (int g = 0; g < 4; ++g){
            int cb = ct*32 + 8*g + 4*hiK;
            float4 c4 = *reinterpret_cast<const float4*>(cterm   + (size_t)sgt*Dd + cb);
            float4 t4 = *reinterpret_cast<const float4*>(h_trans + (size_t)sgt*Dd + cb);
            unsigned long long hb = *reinterpret_cast<const unsigned long long*>(
                Al + lNode*512 + ((((ct*4 + g)*16) ^ swz) + 8*hiK));
            float h0 = bf2f((unsigned short)(hb      ));
            float h1 = bf2f((unsigned short)(hb >> 16));
            float h2 = bf2f((unsigned short)(hb >> 32));
            float h3 = bf2f((unsigned short)(hb >> 48));
            float4 o4; float z;
            z = rcp_(1.f + exp2f(-LOG2E*(acc[4*g+0] + c4.x))); o4.x = fmaf(z, t4.x - h0, h0);
            z = rcp_(1.f + exp2f(-LOG2E*(acc[4*g+1] + c4.y))); o4.y = fmaf(z, t4.y - h1, h1);
            z = rcp_(1.f + exp2f(-LOG2E*(acc[4*g+2] + c4.z))); o4.z = fmaf(z, t4.z - h2, h2);
            z = rcp_(1.f + exp2f(-LOG2E*(acc[4*g+3] + c4.w))); o4.w = fmaf(z, t4.w - h3, h3);
            *reinterpret_cast<float4*>(out + (size_t)nodeG*Dd + cb) = o4;
        }
        __syncthreads();   // protect Al before next chunk
    }
}

// ---------------- per-cluster ctx partials: 4 chunk-blocks per cluster, no atomics ----------------
__global__ __launch_bounds__(256)
void k_ctx(const float* __restrict__ h, const float* __restrict__ e,
           const int* __restrict__ order, const int* __restrict__ hist,
           const int* __restrict__ offs,
           float* __restrict__ ctxPart, float* __restrict__ denPart){
    int b = blockIdx.x;
    int c = b >> 2, q = b & 3;
    int cnt = hist[c*PAD], start0 = offs[c];
    int c0 = (cnt * q) >> 2, c1 = (cnt * (q+1)) >> 2;
    int n = c1 - c0;
    int start = start0 + c0;
    int t = threadIdx.x;
    __shared__ int idxL[512];
    __shared__ float eL[512];
    __shared__ float redL[4][256];
    __shared__ float dsum[4];
    int r4 = t >> 6;
    int col4 = (t & 63) << 2;
    float ax = 0.f, ay = 0.f, az = 0.f, aw = 0.f;
    float dpart = 0.f;
    for (int base = 0; base < n; base += 512){
        int m = min(512, n - base);
        for (int i = t; i < m; i += 256){
            int nd = order[start + base + i];
            idxL[i] = nd;
            float ev = e[nd];
            eL[i] = ev;
            dpart += ev;
        }
        __syncthreads();
        #pragma unroll 4
        for (int i = r4; i < m; i += 4){
            float ev = eL[i];
            float4 hv = *reinterpret_cast<const float4*>(h + (size_t)idxL[i]*Dd + col4);
            ax = fmaf(ev, hv.x, ax);
            ay = fmaf(ev, hv.y, ay);
            az = fmaf(ev, hv.z, az);
            aw = fmaf(ev, hv.w, aw);
        }
        __syncthreads();
    }
    *reinterpret_cast<float4*>(&redL[r4][col4]) = (float4){ax, ay, az, aw};
    #pragma unroll
    for (int off = 1; off < 64; off <<= 1) dpart += __shfl_xor(dpart, off);
    if ((t & 63) == 0) dsum[r4] = dpart;
    __syncthreads();
    if (t < 256){
        float s = redL[0][t] + redL[1][t] + redL[2][t] + redL[3][t];
        ctxPart[((size_t)c*4 + q)*Dd + t] = s;
    }
    if (t == 0) denPart[b] = dsum[0] + dsum[1] + dsum[2] + dsum[3];
}

// ---------------- virtual-node side (1 cluster/block) ----------------
__global__ __launch_bounds__(256)
void k_vn(const float* __restrict__ ctxPart, const float* __restrict__ denPart,
          const float* __restrict__ g_hat,
          const float* __restrict__ Wv, const float* __restrict__ bv,
          const float* __restrict__ H2w, const float* __restrict__ H2b,
          const float* __restrict__ G2w, const float* __restrict__ G2b,
          float* __restrict__ out){
    int c = blockIdx.x, d = threadIdx.x;
    __shared__ float cL[Dd], gtL[Dd], ghL[Dd];
    float den = denPart[c*4] + denPart[c*4+1] + denPart[c*4+2] + denPart[c*4+3];
    float inv = (den > 0.f) ? 1.f/den : 0.f;
    float num = ctxPart[((size_t)c*4 + 0)*Dd + d] + ctxPart[((size_t)c*4 + 1)*Dd + d]
              + ctxPart[((size_t)c*4 + 2)*Dd + d] + ctxPart[((size_t)c*4 + 3)*Dd + d];
    cL[d]  = num * inv;
    ghL[d] = g_hat[(size_t)c*Dd + d];
    __syncthreads();
    float a1 = bv[d];
    #pragma unroll 4
    for (int k = 0; k < Dd; ++k) a1 = fmaf(cL[k], Wv[k*Dd + d], a1);
    float gt = tanhf(a1);
    gtL[d] = gt;
    __syncthreads();
    float a2 = H2b[d] + G2b[d];
    #pragma unroll 4
    for (int k = 0; k < Dd; ++k){
        a2 = fmaf(gtL[k], H2w[k*Dd + d], a2);
        a2 = fmaf(ghL[k], G2w[k*Dd + d], a2);
    }
    float z = 1.f / (1.f + expf(-a2));
    out[(size_t)(Nn + c)*Dd + d] = (1.f - z)*gt + z*ghL[d];
}

extern "C" void kernel_launch(void* const* d_in, const int* in_sizes, int n_in,
                              void* d_out, int out_size, void* d_ws, size_t ws_size,
                              hipStream_t stream){
    const float* h       = (const float*)d_in[0];
    const float* g       = (const float*)d_in[1];
    const float* g_hat   = (const float*)d_in[2];
    const int*   seg     = (const int*)  d_in[3];
    const float* Wq      = (const float*)d_in[4];
    const float* Wk      = (const float*)d_in[5];
    const float* b_attn  = (const float*)d_in[6];
    const float* w_score = (const float*)d_in[7];
    const float* b_score = (const float*)d_in[8];
    const float* Wv      = (const float*)d_in[9];
    const float* bv      = (const float*)d_in[10];
    const float* Ws      = (const float*)d_in[11];
    const float* bs      = (const float*)d_in[12];
    const float* H1w     = (const float*)d_in[13];
    const float* H1b     = (const float*)d_in[14];
    const float* G1w     = (const float*)d_in[15];
    const float* G1b     = (const float*)d_in[16];
    const float* H2w     = (const float*)d_in[17];
    const float* H2b     = (const float*)d_in[18];
    const float* G2w     = (const float*)d_in[19];
    const float* G2b     = (const float*)d_in[20];
    float* out = (float*)d_out;

    char* ws = (char*)d_ws;
    unsigned short* wfragK = (unsigned short*)(ws + 0);      //   131,072 B
    unsigned short* wfragH = (unsigned short*)(ws + 131072); //   131,072 B
    float* qb      = (float*)(ws +  262144);                 // 1,024,000 B
    float* h_trans = (float*)(ws + 1286144);                 // 1,024,000 B
    float* cterm   = (float*)(ws + 2310144);                 // 1,024,000 B
    float* e       = (float*)(ws + 3334144);                 //   800,000 B
    int*   order   = (int*)  (ws + 4134144);                 //   800,000 B
    int*   hist    = (int*)  (ws + 4934144);                 //    64,000 B (padded x16)
    int*   offs    = (int*)  (ws + 4998144);                 //     4,000 B
    int*   cursor  = (int*)  (ws + 5002144);                 //    64,000 B (padded x16)
    float* ctxPart = (float*)(ws + 5066144);                 // 4,096,000 B
    float* denPart = (float*)(ws + 9162144);                 //    16,000 B

    hipLaunchKernelGGL(k_prep, dim3(64), dim3(256), 0, stream, Wk, H1w, wfragK, wfragH, hist);
    hipLaunchKernelGGL(k_cluster_prep, dim3(Cc), dim3(256), 0, stream,
                       g, Wq, b_attn, Ws, bs, G1w, G1b, H1b, seg, hist, qb, h_trans, cterm);
    hipLaunchKernelGGL(k_scan, dim3(1), dim3(1024), 0, stream, hist, offs, cursor);
    hipLaunchKernelGGL(k_scatter, dim3((Nn + 255)/256), dim3(256), 0, stream, seg, cursor, order);
    hipLaunchKernelGGL(k_score, dim3(GBLK), dim3(512), 0, stream,
                       h, wfragK, seg, qb, w_score, b_score, e);
    hipLaunchKernelGGL(k_merge, dim3(GBLK), dim3(512), 0, stream,
                       h, wfragH, seg, cterm, h_trans, out);
    hipLaunchKernelGGL(k_ctx, dim3(Cc*4), dim3(256), 0, stream, h, e, order, hist, offs, ctxPart, denPart);
    hipLaunchKernelGGL(k_vn, dim3(Cc), dim3(256), 0, stream,
                       ctxPart, denPart, g_hat, Wv, bv, H2w, H2b, G2w, G2b, out);
}